// Round 13
// baseline (76.916 us; speedup 1.0000x reference)
//
#include <hip/hip_runtime.h>
#include <math.h>

#define NN 512
#define MM 100
#define TPB 256
#define ROWS_OUT 4            // output rows per strip
#define ROWS_LDS 13           // staged input-row window
#define PLANES_PER_BLOCK 8

typedef float f32x2 __attribute__((ext_vector_type(2)));
typedef unsigned int u32;
typedef u32 u32x2 __attribute__((ext_vector_type(2)));
typedef u32 u32x4 __attribute__((ext_vector_type(4)));

// ws layout (floats): B_u[51200] | B_v[51200] | pk[2*262144 u32] | strip_tab[256]

__global__ void bcoef_kernel(const float* __restrict__ c_u,
                             const float* __restrict__ c_v,
                             float* __restrict__ B_u,
                             float* __restrict__ B_v) {
    __shared__ float sSt[MM];
    int x = blockIdx.x;
    int j = threadIdx.x;
    if (j < MM) {
        double arg = M_PI * ((double)x / (double)(NN - 1)) * (double)(j + 1);
        sSt[j] = (float)sin(arg);
    }
    __syncthreads();
    if (j >= MM) return;
    float au = 0.f, av = 0.f;
    for (int i = 0; i < MM; ++i) {
        int i1 = i + 1, j1 = j + 1;
        int r2i = i1 * i1 + j1 * j1;
        float w = (r2i <= 10100) ? (1.0f / sqrtf((float)r2i)) : 0.0f;
        float sw = sSt[i] * w;
        au += sw * c_u[i * MM + j];
        av += sw * c_v[i * MM + j];
    }
    B_u[j * NN + x] = au;
    B_v[j * NN + x] = av;
}

// Fused field + compressed per-px remap table: 8 B/px, L2-resident.
// pk[pix] = { offA | offB<<16 (window-rebased), xv_u16 | yv_u16<<16 }.
__global__ __launch_bounds__(256)
void field_weights_kernel(const float* __restrict__ B_u,
                          const float* __restrict__ B_v,
                          float scale,
                          u32x2* __restrict__ pk,
                          int* __restrict__ strip_tab) {
    __shared__ float sS[ROWS_OUT * MM];
    __shared__ int s_mn[4], s_mx[4];
    int t = threadIdx.x;
    int strip = blockIdx.x;
    int y0 = strip * ROWS_OUT;

    for (int i = t; i < ROWS_OUT * MM; i += 256) {
        int r = i / MM, j = i % MM;
        double arg = M_PI * ((double)(y0 + r) / (double)(NN - 1)) * (double)(j + 1);
        sS[i] = (float)sin(arg);
    }
    __syncthreads();

    float au[ROWS_OUT][2] = {}, av[ROWS_OUT][2] = {};
    for (int j = 0; j < MM; ++j) {
        float bu0 = B_u[j * NN + t], bu1 = B_u[j * NN + t + 256];
        float bv0 = B_v[j * NN + t], bv1 = B_v[j * NN + t + 256];
        #pragma unroll
        for (int r = 0; r < ROWS_OUT; ++r) {
            float s = sS[r * MM + j];        // wave-uniform -> broadcast
            au[r][0] += bu0 * s; au[r][1] += bu1 * s;
            av[r][0] += bv0 * s; av[r][1] += bv1 * s;
        }
    }

    float xvq[8], yvq[8];
    int offA[8], offB[8];
    int myf = NN, Myc = -1;
    #pragma unroll
    for (int i = 0; i < 8; ++i) {
        int c = i & 1, r = i >> 1;
        int xi = (c << 8) + t;
        int yi = y0 + r;
        float xn = fminf(fmaxf((float)xi - scale * au[r][c], 0.0f), (float)(NN - 1));
        float yn = fminf(fmaxf((float)yi - scale * av[r][c], 0.0f), (float)(NN - 1));
        int xf = (int)floorf(xn), yf = (int)floorf(yn);
        int yc = (int)ceilf(yn);
        xvq[i] = xn - (float)xf;
        yvq[i] = yn - (float)yf;
        offA[i] = (yf << 9) + xf;
        offB[i] = (yc << 9) + xf;
        myf = min(myf, yf);
        Myc = max(Myc, yc);
    }

    for (int d = 32; d; d >>= 1) {
        myf = min(myf, __shfl_xor(myf, d));
        Myc = max(Myc, __shfl_xor(Myc, d));
    }
    int wid = t >> 6;
    if ((t & 63) == 0) { s_mn[wid] = myf; s_mx[wid] = Myc; }
    __syncthreads();
    int r0 = min(min(s_mn[0], s_mn[1]), min(s_mn[2], s_mn[3]));
    int nr = max(max(s_mx[0], s_mx[1]), max(s_mx[2], s_mx[3])) - r0 + 1;
    if (t == 0) { strip_tab[2 * strip] = r0; strip_tab[2 * strip + 1] = nr; }

    int rb = r0 << 9;
    #pragma unroll
    for (int i = 0; i < 8; ++i) {
        int pix = ((y0 + (i >> 1)) << 9) + ((i & 1) << 8) + t;
        u32 oa = (u32)(offA[i] - rb);          // fits 16 bits for nr <= 127
        u32 ob = (u32)(offB[i] - rb);
        u32 xq = (u32)__float2int_rn(xvq[i] * 65535.0f);
        u32 yq = (u32)__float2int_rn(yvq[i] * 65535.0f);
        u32x2 v; v[0] = oa | (ob << 16); v[1] = xq | (yq << 16);
        pk[pix] = v;
    }
}

// 8 planes per block, double-buffered LDS, stage-ahead pipeline:
// issue DMA(p+1, buf^1) -> compute(p, buf) -> barrier (vmcnt drain lands
// AFTER compute, hiding DMA latency). pk table loaded ONCE into 16 VGPRs.
__global__ __launch_bounds__(TPB, 3)
void remap_kernel(const float* __restrict__ img,
                  const u32x2* __restrict__ pk,
                  const int* __restrict__ strip_tab,
                  float* __restrict__ out,
                  int planes) {
    __shared__ __align__(16) float rows[2][ROWS_LDS * NN + 4];

    // XCD-bijective swizzle (gridDim.x % 8 == 0), plane-group-major:
    // adjacent strips (sharing halo + table slices) adjacent on one XCD.
    int nb = gridDim.x;
    int bid = blockIdx.x;
    int sid = (bid & 7) * (nb >> 3) + (bid >> 3);
    int pg    = sid >> 7;        // plane group (8 planes)
    int strip = sid & 127;

    int t = threadIdx.x;
    int r0 = strip_tab[2 * strip];
    int nr = strip_tab[2 * strip + 1];
    int base = ((strip * ROWS_OUT) << 9) + (t << 1);   // x = 2t, 2t+1

    // plane-invariant table: 4 x u32x4 = 16 VGPRs, loaded once
    const u32x4* __restrict__ pk4 = (const u32x4*)pk;
    u32x4 pr[ROWS_OUT];
    #pragma unroll
    for (int r = 0; r < ROWS_OUT; ++r) pr[r] = pk4[(base + (r << 9)) >> 1];

    int p0 = pg * PLANES_PER_BLOCK;
    int p1 = p0 + PLANES_PER_BLOCK; if (p1 > planes) p1 = planes;
    const float qs = 1.0f / 65535.0f;

    if (nr <= ROWS_LDS) {
        if (t == 0) { rows[0][nr * NN] = 0.f; rows[1][nr * NN] = 0.f; }

        int nbytes = nr << 11;
        int wave = t >> 6;
        int lane_goff = t * 16;
        size_t rbo = (size_t)(r0 << 9);

        // prologue: stage plane p0 into buf 0
        {
            const char* ipc = (const char*)(img + (size_t)p0 * (NN * NN) + rbo);
            for (int ob = 0; ob < nbytes; ob += TPB * 16) {
                if (ob + wave * 1024 < nbytes) {
                    __builtin_amdgcn_global_load_lds(
                        (const __attribute__((address_space(1))) void*)(ipc + ob + lane_goff),
                        (__attribute__((address_space(3))) void*)((char*)rows[0] + ob + wave * 1024),
                        16, 0, 0);
                }
            }
        }
        __syncthreads();

        int cur = 0;
        for (int p = p0; p < p1; ++p) {
            // stage-ahead: issue next plane's DMA before computing current
            if (p + 1 < p1) {
                const char* ipc = (const char*)(img + (size_t)(p + 1) * (NN * NN) + rbo);
                for (int ob = 0; ob < nbytes; ob += TPB * 16) {
                    if (ob + wave * 1024 < nbytes) {
                        __builtin_amdgcn_global_load_lds(
                            (const __attribute__((address_space(1))) void*)(ipc + ob + lane_goff),
                            (__attribute__((address_space(3))) void*)((char*)rows[cur ^ 1] + ob + wave * 1024),
                            16, 0, 0);
                    }
                }
            }

            const float* __restrict__ rw = rows[cur];
            float* __restrict__ op = out + (size_t)p * (NN * NN);
            #pragma unroll
            for (int r = 0; r < ROWS_OUT; ++r) {
                u32x4 pp = pr[r];
                int oA0 = (int)(pp[0] & 0xFFFFu), oB0 = (int)(pp[0] >> 16);
                float xv0 = (float)(pp[1] & 0xFFFFu) * qs;
                float yv0 = (float)(pp[1] >> 16) * qs;
                int oA1 = (int)(pp[2] & 0xFFFFu), oB1 = (int)(pp[2] >> 16);
                float xv1 = (float)(pp[3] & 0xFFFFu) * qs;
                float yv1 = (float)(pp[3] >> 16) * qs;
                float t0 = (1.f - xv0) * rw[oA0] + xv0 * rw[oA0 + 1];
                float b0 = (1.f - xv0) * rw[oB0] + xv0 * rw[oB0 + 1];
                float t1 = (1.f - xv1) * rw[oA1] + xv1 * rw[oA1 + 1];
                float b1 = (1.f - xv1) * rw[oB1] + xv1 * rw[oB1 + 1];
                f32x2 o;
                o[0] = (1.f - yv0) * t0 + yv0 * b0;
                o[1] = (1.f - yv1) * t1 + yv1 * b1;
                __builtin_nontemporal_store(o, (f32x2*)(op + base + (r << 9)));
            }
            __syncthreads();   // drains vmcnt AFTER compute -> latency hidden
            cur ^= 1;
        }
    } else {
        // fallback: direct global gathers per plane (correct for any dy)
        int rb = r0 << 9;
        for (int p = p0; p < p1; ++p) {
            const float* __restrict__ ip = img + (size_t)p * (NN * NN);
            float* __restrict__ op = out + (size_t)p * (NN * NN);
            #pragma unroll
            for (int r = 0; r < ROWS_OUT; ++r) {
                u32x4 pp = pr[r];
                int a0 = (int)(pp[0] & 0xFFFFu) + rb, b0i = (int)(pp[0] >> 16) + rb;
                float xv0 = (float)(pp[1] & 0xFFFFu) * qs;
                float yv0 = (float)(pp[1] >> 16) * qs;
                int a1 = (int)(pp[2] & 0xFFFFu) + rb, b1i = (int)(pp[2] >> 16) + rb;
                float xv1 = (float)(pp[3] & 0xFFFFu) * qs;
                float yv1 = (float)(pp[3] >> 16) * qs;
                int e0 = ((a0 & 511) == 511) ? 0 : 1;
                int e1 = ((a1 & 511) == 511) ? 0 : 1;
                float t0 = (1.f - xv0) * ip[a0] + xv0 * ip[a0 + e0];
                float bo0 = (1.f - xv0) * ip[b0i] + xv0 * ip[b0i + e0];
                float t1 = (1.f - xv1) * ip[a1] + xv1 * ip[a1 + e1];
                float bo1 = (1.f - xv1) * ip[b1i] + xv1 * ip[b1i + e1];
                f32x2 o;
                o[0] = (1.f - yv0) * t0 + yv0 * bo0;
                o[1] = (1.f - yv1) * t1 + yv1 * bo1;
                __builtin_nontemporal_store(o, (f32x2*)(op + base + (r << 9)));
            }
        }
    }
}

extern "C" void kernel_launch(void* const* d_in, const int* in_sizes, int n_in,
                              void* d_out, int out_size, void* d_ws, size_t ws_size,
                              hipStream_t stream) {
    const float* img = (const float*)d_in[0];
    const float* c_u = (const float*)d_in[1];
    const float* c_v = (const float*)d_in[2];
    float* out = (float*)d_out;

    int planes = in_sizes[0] / (NN * NN);   // 96

    float* ws   = (float*)d_ws;
    float* B_u  = ws;                        // 51200
    float* B_v  = B_u + MM * NN;             // 51200
    u32x2* pk   = (u32x2*)(ws + 2 * MM * NN);            // 2 MB
    int* strip_tab = (int*)(ws + 2 * MM * NN + 2 * NN * NN);

    double log_cut = log((double)MM + 1e-6);
    double T1 = 1.0 / (M_PI * (double)NN * (double)NN * log_cut);
    double T2 = 4.0 / (M_PI * M_PI * M_PI * (double)MM * (double)MM * log_cut);
    if (T2 < T1) T2 = T1;
    double T = 0.5 * (T1 + T2);
    float scale = (float)(sqrt(T) * (double)NN);

    bcoef_kernel<<<NN, 128, 0, stream>>>(c_u, c_v, B_u, B_v);
    field_weights_kernel<<<NN / ROWS_OUT, 256, 0, stream>>>(B_u, B_v, scale,
                                                            pk, strip_tab);

    int strips = NN / ROWS_OUT;                                      // 128
    int groups = (planes + PLANES_PER_BLOCK - 1) / PLANES_PER_BLOCK; // 12
    remap_kernel<<<strips * groups, TPB, 0, stream>>>(img, pk, strip_tab,
                                                      out, planes);
}